// Round 1
// baseline (491.792 us; speedup 1.0000x reference)
//
#include <hip/hip_runtime.h>

typedef __bf16 bf16x8 __attribute__((ext_vector_type(8)));
typedef float f32x4 __attribute__((ext_vector_type(4)));

__device__ __forceinline__ unsigned short f2bf(float f) {
    union { float f; unsigned u; } v; v.f = f;
    unsigned r = v.u + 0x7FFFu + ((v.u >> 16) & 1u);   // round-to-nearest-even
    return (unsigned short)(r >> 16);
}
__device__ __forceinline__ float bf2f(unsigned short h) {
    union { unsigned u; float f; } v; v.u = ((unsigned)h) << 16; return v.f;
}

// ---------------------------------------------------------------------------
// Transpose fp32 [batch][S][D] -> bf16 [batch][D][S]
// grid: (S/32, D/32, batch), block: 256
// ---------------------------------------------------------------------------
__global__ __launch_bounds__(256) void transpose_to_bf16(
    const float* __restrict__ src, unsigned short* __restrict__ dst, int S, int D)
{
    __shared__ float tile[32][33];
    const float* sb = src + (size_t)blockIdx.z * S * D;
    unsigned short* db = dst + (size_t)blockIdx.z * S * D;
    const int s0 = blockIdx.x * 32, d0 = blockIdx.y * 32;
    const int t = threadIdx.x;
    const int tr = t >> 5, tc = t & 31;
#pragma unroll
    for (int i = 0; i < 4; i++) {
        int s = s0 + tr + i * 8;
        tile[tr + i * 8][tc] = sb[(size_t)s * D + d0 + tc];
    }
    __syncthreads();
#pragma unroll
    for (int i = 0; i < 4; i++) {
        int d = d0 + tr + i * 8;
        db[(size_t)d * S + s0 + tc] = f2bf(tile[tc][tr + i * 8]);
    }
}

// ---------------------------------------------------------------------------
// 128x128-tile bf16 GEMM, C = A @ Bt^T   (A: [M,K], Bt: [N,K] both row-major)
// AMODE 0: A is bf16 (global_load_lds staging); AMODE 1: A is fp32 (convert)
// CMODE 0: relu -> bf16 out; CMODE 1: *scale -> bf16 out; CMODE 2: fp32 out
// block: 256 (4 waves, 2x2 wave grid, each wave 64x64 via 4x4 16x16x32 MFMA)
// ---------------------------------------------------------------------------
template<int AMODE, int CMODE>
__global__ __launch_bounds__(256, 2) void gemm_bt(
    const void* __restrict__ Aptr, const unsigned short* __restrict__ Bt,
    void* __restrict__ Cptr, int K, float scale,
    long long aStride, long long bStride, long long cStride, int ldc)
{
    __shared__ __align__(16) unsigned short As[128 * 32];
    __shared__ __align__(16) unsigned short Bs[128 * 32];

    const int t = threadIdx.x;
    const int lane = t & 63;
    const int wave = t >> 6;
    const int z = blockIdx.z;

    const unsigned short* Ab16 = (const unsigned short*)Aptr + (size_t)z * aStride;
    const float*          Af32 = (const float*)Aptr + (size_t)z * aStride;
    const unsigned short* B    = Bt + (size_t)z * bStride;

    const int rowA = blockIdx.y * 128;
    const int rowB = blockIdx.x * 128;

    f32x4 acc[4][4];
#pragma unroll
    for (int i = 0; i < 4; i++)
#pragma unroll
        for (int j = 0; j < 4; j++) acc[i][j] = f32x4{0.f, 0.f, 0.f, 0.f};

    const int wm = (wave >> 1) * 64;
    const int wn = (wave & 1) * 64;
    const int lrow = lane & 15;
    const int lk = (lane >> 4) * 8;

    for (int kt = 0; kt < K; kt += 32) {
        {   // stage B tile (bf16, async direct-to-LDS, 16B/lane)
            const int r = lane >> 2;
            const int kk = (lane & 3) * 8;
            const int c0 = wave, c1 = wave + 4;
            const unsigned short* g0 = B + (size_t)(rowB + c0 * 16 + r) * K + kt + kk;
            const unsigned short* g1 = B + (size_t)(rowB + c1 * 16 + r) * K + kt + kk;
            __builtin_amdgcn_global_load_lds((const __attribute__((address_space(1))) void*)g0,
                                             (__attribute__((address_space(3))) void*)&Bs[c0 * 512], 16, 0, 0);
            __builtin_amdgcn_global_load_lds((const __attribute__((address_space(1))) void*)g1,
                                             (__attribute__((address_space(3))) void*)&Bs[c1 * 512], 16, 0, 0);
        }
        if constexpr (AMODE == 0) {
            const int r = lane >> 2;
            const int kk = (lane & 3) * 8;
            const int c0 = wave, c1 = wave + 4;
            const unsigned short* g0 = Ab16 + (size_t)(rowA + c0 * 16 + r) * K + kt + kk;
            const unsigned short* g1 = Ab16 + (size_t)(rowA + c1 * 16 + r) * K + kt + kk;
            __builtin_amdgcn_global_load_lds((const __attribute__((address_space(1))) void*)g0,
                                             (__attribute__((address_space(3))) void*)&As[c0 * 512], 16, 0, 0);
            __builtin_amdgcn_global_load_lds((const __attribute__((address_space(1))) void*)g1,
                                             (__attribute__((address_space(3))) void*)&As[c1 * 512], 16, 0, 0);
        } else {
            // fp32 A: load float4, convert to bf16, write LDS
#pragma unroll
            for (int i = 0; i < 4; i++) {
                int q = t + i * 256;       // 0..1023 quad index
                int r = q >> 3;            // row 0..127
                int qq = q & 7;            // float4 within row
                float4 v = *(const float4*)(Af32 + (size_t)(rowA + r) * K + kt + qq * 4);
                union { unsigned short u[4]; uint2 p; } pk;
                pk.u[0] = f2bf(v.x); pk.u[1] = f2bf(v.y);
                pk.u[2] = f2bf(v.z); pk.u[3] = f2bf(v.w);
                *(uint2*)&As[r * 32 + qq * 4] = pk.p;
            }
        }
        __syncthreads();

        bf16x8 a[4], b[4];
#pragma unroll
        for (int i = 0; i < 4; i++) a[i] = *(const bf16x8*)&As[(wm + i * 16 + lrow) * 32 + lk];
#pragma unroll
        for (int j = 0; j < 4; j++) b[j] = *(const bf16x8*)&Bs[(wn + j * 16 + lrow) * 32 + lk];
#pragma unroll
        for (int i = 0; i < 4; i++)
#pragma unroll
            for (int j = 0; j < 4; j++)
                acc[i][j] = __builtin_amdgcn_mfma_f32_16x16x32_bf16(a[i], b[j], acc[i][j], 0, 0, 0);
        __syncthreads();
    }

    // epilogue: C/D layout col=lane&15, row=(lane>>4)*4+reg
    const int orow = (lane >> 4) * 4;
    const int ocol = lane & 15;
    if constexpr (CMODE == 2) {
        float* C = (float*)Cptr + (size_t)z * cStride;
#pragma unroll
        for (int i = 0; i < 4; i++)
#pragma unroll
            for (int j = 0; j < 4; j++) {
                int col = rowB + wn + j * 16 + ocol;
#pragma unroll
                for (int r = 0; r < 4; r++) {
                    int rw = rowA + wm + i * 16 + orow + r;
                    C[(size_t)rw * ldc + col] = acc[i][j][r];
                }
            }
    } else {
        unsigned short* C = (unsigned short*)Cptr + (size_t)z * cStride;
#pragma unroll
        for (int i = 0; i < 4; i++)
#pragma unroll
            for (int j = 0; j < 4; j++) {
                int col = rowB + wn + j * 16 + ocol;
#pragma unroll
                for (int r = 0; r < 4; r++) {
                    int rw = rowA + wm + i * 16 + orow + r;
                    float v = acc[i][j][r];
                    if (CMODE == 0) v = fmaxf(v, 0.f);
                    else            v *= scale;
                    C[(size_t)rw * ldc + col] = f2bf(v);
                }
            }
    }
}

// ---------------------------------------------------------------------------
// Masked softmax over last dim (Sk=1024), bf16 in-place. One block per row.
// Mimics reference: masked -> -1e30, subtract rowmax, exp, normalize.
// ---------------------------------------------------------------------------
__global__ __launch_bounds__(256) void softmax_mask_kernel(
    unsigned short* __restrict__ score, const int* __restrict__ mask, int Sq, int Sk)
{
    const int row = blockIdx.x;
    const int b = row / Sq;
    unsigned short* s = score + (size_t)row * Sk;
    const int* mk = mask + (size_t)b * Sk;
    const int t = threadIdx.x;

    float v[4];
    float mx = -3.0e38f;
#pragma unroll
    for (int e = 0; e < 4; e++) {
        int k = t + e * 256;
        float lv = bf2f(s[k]);
        v[e] = (mk[k] != 0) ? lv : -1.0e30f;
        mx = fmaxf(mx, v[e]);
    }
#pragma unroll
    for (int off = 32; off > 0; off >>= 1) mx = fmaxf(mx, __shfl_down(mx, off, 64));

    __shared__ float sm[4], ssum[4], fin[2];
    const int wv = t >> 6, ln = t & 63;
    if (ln == 0) sm[wv] = mx;
    __syncthreads();
    if (t == 0) fin[0] = fmaxf(fmaxf(sm[0], sm[1]), fmaxf(sm[2], sm[3]));
    __syncthreads();
    mx = fin[0];

    float sum = 0.f;
#pragma unroll
    for (int e = 0; e < 4; e++) { v[e] = __expf(v[e] - mx); sum += v[e]; }
#pragma unroll
    for (int off = 32; off > 0; off >>= 1) sum += __shfl_down(sum, off, 64);
    if (ln == 0) ssum[wv] = sum;
    __syncthreads();
    if (t == 0) fin[1] = ssum[0] + ssum[1] + ssum[2] + ssum[3];
    __syncthreads();

    const float inv = 1.0f / fin[1];
#pragma unroll
    for (int e = 0; e < 4; e++) s[t + e * 256] = f2bf(v[e] * inv);
}

// ---------------------------------------------------------------------------
// Copy inputs fp32 -> out[..., 512:1024] (concat right half), float4
// ---------------------------------------------------------------------------
__global__ __launch_bounds__(256) void copy_inputs_kernel(
    const float4* __restrict__ in, float4* __restrict__ out)
{
    int i = blockIdx.x * 256 + threadIdx.x;   // 4194304 total
    int bq = i >> 7;                          // 128 float4 per 512-float row
    int d  = i & 127;
    out[(size_t)bq * 256 + 128 + d] = in[i];
}

extern "C" void kernel_launch(void* const* d_in, const int* in_sizes, int n_in,
                              void* d_out, int out_size, void* d_ws, size_t ws_size,
                              hipStream_t stream)
{
    const float* inputs = (const float*)d_in[0];   // [32,1024,512]
    const float* memory = (const float*)d_in[1];   // [32,1024,512]
    const int*   mmask  = (const int*)d_in[2];     // [32,1024]
    const float* W_in   = (const float*)d_in[3];   // [512,512]
    const float* W_mem  = (const float*)d_in[4];   // [512,512]
    float* out = (float*)d_out;                    // [32,1024,1024]

    char* ws = (char*)d_ws;
    unsigned short* Wt_in  = (unsigned short*)(ws);                               // 512 KiB
    unsigned short* Wt_mem = (unsigned short*)(ws + 524288);                      // 512 KiB
    unsigned short* Xq     = (unsigned short*)(ws + 1048576);                     // 32 MiB
    unsigned short* Xm     = (unsigned short*)(ws + 1048576 + 33554432ull);       // 32 MiB
    unsigned short* MemT   = (unsigned short*)(ws + 1048576 + 2*33554432ull);     // 32 MiB
    unsigned short* Score  = (unsigned short*)(ws + 1048576 + 3*33554432ull);     // 64 MiB

    const float scale = 0.04419417382415922f;  // 1/sqrt(512)

    // 1. weight transposes + memory^T (all -> bf16)
    transpose_to_bf16<<<dim3(16, 16, 1), 256, 0, stream>>>(W_in,  Wt_in,  512, 512);
    transpose_to_bf16<<<dim3(16, 16, 1), 256, 0, stream>>>(W_mem, Wt_mem, 512, 512);
    transpose_to_bf16<<<dim3(32, 16, 32), 256, 0, stream>>>(memory, MemT, 1024, 512);

    // 2. projections: x = relu(inputs @ W_in), m = relu(memory @ W_mem)  (fp32 A)
    gemm_bt<1, 0><<<dim3(4, 256, 1), 256, 0, stream>>>(
        inputs, Wt_in, Xq, 512, 0.f, 0, 0, 0, 512);
    gemm_bt<1, 0><<<dim3(4, 256, 1), 256, 0, stream>>>(
        memory, Wt_mem, Xm, 512, 0.f, 0, 0, 0, 512);

    // 3. logits = x @ m^T * scale  -> bf16 Score  (batched)
    gemm_bt<0, 1><<<dim3(8, 8, 32), 256, 0, stream>>>(
        Xq, Xm, Score, 512, scale, 1024ll * 512, 1024ll * 512, 1024ll * 1024, 1024);

    // 4. masked softmax in-place on Score
    softmax_mask_kernel<<<32768, 256, 0, stream>>>(Score, mmask, 1024, 1024);

    // 5. context = Score @ memory  -> fp32 out[..., 0:512]  (batched, ldc=1024)
    gemm_bt<0, 2><<<dim3(4, 8, 32), 256, 0, stream>>>(
        Score, MemT, out, 1024, 1.f, 1024ll * 1024, 512ll * 1024, 1024ll * 1024, 1024);

    // 6. concat right half: out[..., 512:1024] = inputs
    copy_inputs_kernel<<<16384, 256, 0, stream>>>((const float4*)inputs, (float4*)out);
}

// Round 2
// 454.219 us; speedup vs baseline: 1.0827x; 1.0827x over previous
//
#include <hip/hip_runtime.h>

typedef __bf16 bf16x8 __attribute__((ext_vector_type(8)));
typedef float f32x4 __attribute__((ext_vector_type(4)));

__device__ __forceinline__ unsigned short f2bf(float f) {
    union { float f; unsigned u; } v; v.f = f;
    unsigned r = v.u + 0x7FFFu + ((v.u >> 16) & 1u);   // round-to-nearest-even
    return (unsigned short)(r >> 16);
}

// ---------------------------------------------------------------------------
// Transpose fp32 [batch][S][D] -> bf16 [batch][D][S]; optionally also emit the
// straight (non-transposed) bf16 copy. grid: (S/32, D/32, batch), block 256.
// ---------------------------------------------------------------------------
__global__ __launch_bounds__(256) void transpose_to_bf16(
    const float* __restrict__ src, unsigned short* __restrict__ dst,
    unsigned short* __restrict__ dst_copy, int S, int D)
{
    __shared__ float tile[32][33];
    const float* sb = src + (size_t)blockIdx.z * S * D;
    unsigned short* db = dst + (size_t)blockIdx.z * S * D;
    const int s0 = blockIdx.x * 32, d0 = blockIdx.y * 32;
    const int t = threadIdx.x;
    const int tr = t >> 5, tc = t & 31;
#pragma unroll
    for (int i = 0; i < 4; i++) {
        int s = s0 + tr + i * 8;
        float v = sb[(size_t)s * D + d0 + tc];
        tile[tr + i * 8][tc] = v;
        if (dst_copy)
            dst_copy[(size_t)blockIdx.z * S * D + (size_t)s * D + d0 + tc] = f2bf(v);
    }
    __syncthreads();
#pragma unroll
    for (int i = 0; i < 4; i++) {
        int d = d0 + tr + i * 8;
        db[(size_t)d * S + s0 + tc] = f2bf(tile[tc][tr + i * 8]);
    }
}

// ---------------------------------------------------------------------------
// Fused: inputs fp32 -> bf16 (for proj GEMM A) AND out[..., 512:1024] = inputs
// ---------------------------------------------------------------------------
__global__ __launch_bounds__(256) void fuse_inputs_kernel(
    const float4* __restrict__ in, uint2* __restrict__ in_bf16, float4* __restrict__ out)
{
    int i = blockIdx.x * 256 + threadIdx.x;   // 4194304 float4s total
    int bq = i >> 7;                          // row index (b*Sq+q), 128 float4/row
    int d  = i & 127;
    float4 v = in[i];
    out[(size_t)bq * 256 + 128 + d] = v;      // concat right half (exact fp32)
    union { unsigned short u[4]; uint2 p; } pk;
    pk.u[0] = f2bf(v.x); pk.u[1] = f2bf(v.y);
    pk.u[2] = f2bf(v.z); pk.u[3] = f2bf(v.w);
    in_bf16[i] = pk.p;
}

// ---------------------------------------------------------------------------
// 128x128-tile bf16 GEMM, C = A @ Bt^T   (A: [M,K], Bt: [N,K] both row-major)
// CMODE 0: relu -> bf16
// CMODE 1: p = mask ? exp(acc*scale) : 0 -> bf16; rowsum += p (atomics)
// CMODE 2: acc / rowsum[row] -> fp32
// block 256: 4 waves in 2x2, each wave 64x64 via 4x4 of 16x16x32 bf16 MFMA
// ---------------------------------------------------------------------------
template<int CMODE>
__global__ __launch_bounds__(256, 2) void gemm_bt(
    const unsigned short* __restrict__ A, const unsigned short* __restrict__ Bt,
    void* __restrict__ Cptr, int K, float scale,
    const int* __restrict__ maskp, float* __restrict__ rowsum,
    long long aStride, long long bStride, long long cStride, int ldc)
{
    __shared__ __align__(16) unsigned short As[128 * 32];
    __shared__ __align__(16) unsigned short Bs[128 * 32];

    const int t = threadIdx.x;
    const int lane = t & 63;
    const int wave = t >> 6;
    const int z = blockIdx.z;

    const unsigned short* Ab = A + (size_t)z * aStride;
    const unsigned short* Bb = Bt + (size_t)z * bStride;

    const int rowA = blockIdx.y * 128;
    const int rowB = blockIdx.x * 128;

    f32x4 acc[4][4];
#pragma unroll
    for (int i = 0; i < 4; i++)
#pragma unroll
        for (int j = 0; j < 4; j++) acc[i][j] = f32x4{0.f, 0.f, 0.f, 0.f};

    const int wm = (wave >> 1) * 64;
    const int wn = (wave & 1) * 64;
    const int lrow = lane & 15;
    const int lk = (lane >> 4) * 8;

    // staging address pattern (wave-uniform LDS base + lane*16B)
    const int sr = lane >> 2;             // row within 16-row strip
    const int skk = (lane & 3) * 8;       // k offset (8 bf16 = 16 B)
    const int c0 = wave, c1 = wave + 4;

    for (int kt = 0; kt < K; kt += 32) {
        const unsigned short* gb0 = Bb + (size_t)(rowB + c0 * 16 + sr) * K + kt + skk;
        const unsigned short* gb1 = Bb + (size_t)(rowB + c1 * 16 + sr) * K + kt + skk;
        __builtin_amdgcn_global_load_lds((const __attribute__((address_space(1))) void*)gb0,
                                         (__attribute__((address_space(3))) void*)&Bs[c0 * 512], 16, 0, 0);
        __builtin_amdgcn_global_load_lds((const __attribute__((address_space(1))) void*)gb1,
                                         (__attribute__((address_space(3))) void*)&Bs[c1 * 512], 16, 0, 0);
        const unsigned short* ga0 = Ab + (size_t)(rowA + c0 * 16 + sr) * K + kt + skk;
        const unsigned short* ga1 = Ab + (size_t)(rowA + c1 * 16 + sr) * K + kt + skk;
        __builtin_amdgcn_global_load_lds((const __attribute__((address_space(1))) void*)ga0,
                                         (__attribute__((address_space(3))) void*)&As[c0 * 512], 16, 0, 0);
        __builtin_amdgcn_global_load_lds((const __attribute__((address_space(1))) void*)ga1,
                                         (__attribute__((address_space(3))) void*)&As[c1 * 512], 16, 0, 0);
        __syncthreads();

        bf16x8 a[4], b[4];
#pragma unroll
        for (int i = 0; i < 4; i++) a[i] = *(const bf16x8*)&As[(wm + i * 16 + lrow) * 32 + lk];
#pragma unroll
        for (int j = 0; j < 4; j++) b[j] = *(const bf16x8*)&Bs[(wn + j * 16 + lrow) * 32 + lk];
#pragma unroll
        for (int i = 0; i < 4; i++)
#pragma unroll
            for (int j = 0; j < 4; j++)
                acc[i][j] = __builtin_amdgcn_mfma_f32_16x16x32_bf16(a[i], b[j], acc[i][j], 0, 0, 0);
        __syncthreads();
    }

    // epilogue: C/D layout col=lane&15, row=(lane>>4)*4+reg
    const int orow = (lane >> 4) * 4;
    const int ocol = lane & 15;

    if constexpr (CMODE == 0) {
        unsigned short* C = (unsigned short*)Cptr + (size_t)z * cStride;
#pragma unroll
        for (int i = 0; i < 4; i++)
#pragma unroll
            for (int j = 0; j < 4; j++) {
                int col = rowB + wn + j * 16 + ocol;
#pragma unroll
                for (int r = 0; r < 4; r++) {
                    int rw = rowA + wm + i * 16 + orow + r;
                    C[(size_t)rw * ldc + col] = f2bf(fmaxf(acc[i][j][r], 0.f));
                }
            }
    } else if constexpr (CMODE == 1) {
        unsigned short* C = (unsigned short*)Cptr + (size_t)z * cStride;
        const int* mk = maskp + (size_t)z * 1024;
        float* rs = rowsum + (size_t)z * 1024;
        int mv[4];
#pragma unroll
        for (int j = 0; j < 4; j++) mv[j] = mk[rowB + wn + j * 16 + ocol];
#pragma unroll
        for (int i = 0; i < 4; i++) {
            float part[4] = {0.f, 0.f, 0.f, 0.f};
#pragma unroll
            for (int j = 0; j < 4; j++) {
                int col = rowB + wn + j * 16 + ocol;
#pragma unroll
                for (int r = 0; r < 4; r++) {
                    float p = mv[j] ? __expf(acc[i][j][r] * scale) : 0.f;
                    part[r] += p;
                    int rw = rowA + wm + i * 16 + orow + r;
                    C[(size_t)rw * ldc + col] = f2bf(p);
                }
            }
#pragma unroll
            for (int r = 0; r < 4; r++) {
                float s = part[r];
                s += __shfl_xor(s, 1, 64);
                s += __shfl_xor(s, 2, 64);
                s += __shfl_xor(s, 4, 64);
                s += __shfl_xor(s, 8, 64);
                if (ocol == 0) atomicAdd(&rs[rowA + wm + i * 16 + orow + r], s);
            }
        }
    } else {  // CMODE == 2: normalize by rowsum, fp32 out
        float* C = (float*)Cptr + (size_t)z * cStride;
        const float* rs = rowsum + (size_t)z * 1024;
#pragma unroll
        for (int i = 0; i < 4; i++) {
            float inv[4];
#pragma unroll
            for (int r = 0; r < 4; r++)
                inv[r] = 1.0f / rs[rowA + wm + i * 16 + orow + r];
#pragma unroll
            for (int j = 0; j < 4; j++) {
                int col = rowB + wn + j * 16 + ocol;
#pragma unroll
                for (int r = 0; r < 4; r++) {
                    int rw = rowA + wm + i * 16 + orow + r;
                    C[(size_t)rw * ldc + col] = acc[i][j][r] * inv[r];
                }
            }
        }
    }
}

extern "C" void kernel_launch(void* const* d_in, const int* in_sizes, int n_in,
                              void* d_out, int out_size, void* d_ws, size_t ws_size,
                              hipStream_t stream)
{
    const float* inputs = (const float*)d_in[0];   // [32,1024,512]
    const float* memory = (const float*)d_in[1];   // [32,1024,512]
    const int*   mmask  = (const int*)d_in[2];     // [32,1024]
    const float* W_in   = (const float*)d_in[3];   // [512,512]
    const float* W_mem  = (const float*)d_in[4];   // [512,512]
    float* out = (float*)d_out;                    // [32,1024,1024]

    char* ws = (char*)d_ws;
    const unsigned long long MB = 1048576ull;
    unsigned short* Wt_in  = (unsigned short*)(ws);                  // 512 KiB
    unsigned short* Wt_mem = (unsigned short*)(ws + 524288);         // 512 KiB
    // region A (64 MiB): InB16+MemB16 during steps 1-4, then P (aliased)
    unsigned short* InB16  = (unsigned short*)(ws + 1 * MB);         // 32 MiB
    unsigned short* MemB16 = (unsigned short*)(ws + 1 * MB + 32 * MB); // 32 MiB
    unsigned short* P      = (unsigned short*)(ws + 1 * MB);         // 64 MiB (alias)
    unsigned short* MemT   = (unsigned short*)(ws + 1 * MB + 64 * MB); // 32 MiB
    unsigned short* Xq     = (unsigned short*)(ws + 1 * MB + 96 * MB); // 32 MiB
    unsigned short* Xm     = (unsigned short*)(ws + 1 * MB + 128 * MB);// 32 MiB
    float*          rowsum = (float*)(ws + 1 * MB + 160 * MB);       // 128 KiB

    const float scale = 0.04419417382415922f;  // 1/sqrt(512)

    // 1. weight transposes; memory: transpose + straight bf16 copy
    transpose_to_bf16<<<dim3(16, 16, 1), 256, 0, stream>>>(W_in,  Wt_in,  nullptr, 512, 512);
    transpose_to_bf16<<<dim3(16, 16, 1), 256, 0, stream>>>(W_mem, Wt_mem, nullptr, 512, 512);
    transpose_to_bf16<<<dim3(32, 16, 32), 256, 0, stream>>>(memory, MemT, MemB16, 1024, 512);

    // 2. inputs -> bf16 + concat right half of out
    fuse_inputs_kernel<<<16384, 256, 0, stream>>>(
        (const float4*)inputs, (uint2*)InB16, (float4*)out);

    // zero rowsum (poisoned 0xAA every launch)
    hipMemsetAsync(rowsum, 0, 32 * 1024 * sizeof(float), stream);

    // 3. projections: x = relu(inputs @ W_in), m = relu(memory @ W_mem)
    gemm_bt<0><<<dim3(4, 256, 1), 256, 0, stream>>>(
        InB16, Wt_in, Xq, 512, 0.f, nullptr, nullptr, 0, 0, 0, 512);
    gemm_bt<0><<<dim3(4, 256, 1), 256, 0, stream>>>(
        MemB16, Wt_mem, Xm, 512, 0.f, nullptr, nullptr, 0, 0, 0, 512);

    // 4. P = mask .* exp(x @ m^T * scale), rowsum via atomics (aliases InB16/MemB16)
    gemm_bt<1><<<dim3(8, 8, 32), 256, 0, stream>>>(
        Xq, Xm, P, 512, scale, mmask, rowsum, 1024ll * 512, 1024ll * 512, 1024ll * 1024, 1024);

    // 5. context = (P @ memory) / rowsum  -> fp32 out[..., 0:512] (ldc=1024)
    gemm_bt<2><<<dim3(4, 8, 32), 256, 0, stream>>>(
        P, MemT, out, 1024, 1.f, nullptr, rowsum, 1024ll * 1024, 512ll * 1024, 1024ll * 1024, 1024);
}

// Round 3
// 438.057 us; speedup vs baseline: 1.1227x; 1.0369x over previous
//
#include <hip/hip_runtime.h>

typedef __bf16 bf16x8 __attribute__((ext_vector_type(8)));
typedef float f32x4 __attribute__((ext_vector_type(4)));

__device__ __forceinline__ unsigned short f2bf(float f) {
    union { float f; unsigned u; } v; v.f = f;
    unsigned r = v.u + 0x7FFFu + ((v.u >> 16) & 1u);   // round-to-nearest-even
    return (unsigned short)(r >> 16);
}

// ---------------------------------------------------------------------------
// Per-batch mask compaction: kidx[b][j] = j-th active k index; cnt[b]; padded[b]
// grid: 32 blocks (one per batch), block 256 (each thread scans 4 elements)
// ---------------------------------------------------------------------------
__global__ __launch_bounds__(256) void mask_scan_kernel(
    const int* __restrict__ mask, int* __restrict__ kidx,
    int* __restrict__ cnt, int* __restrict__ padded)
{
    const int b = blockIdx.x;
    const int* m = mask + b * 1024;
    const int t = threadIdx.x;
    int v[4]; int s = 0;
#pragma unroll
    for (int e = 0; e < 4; e++) { v[e] = (m[t * 4 + e] != 0) ? 1 : 0; s += v[e]; }
    const int lane = t & 63, wv = t >> 6;
    int x = s;
#pragma unroll
    for (int off = 1; off < 64; off <<= 1) {
        int y = __shfl_up(x, off, 64);
        if (lane >= off) x += y;
    }
    __shared__ int wsum[4];
    if (lane == 63) wsum[wv] = x;
    __syncthreads();
    int base = 0;
    for (int w = 0; w < wv; w++) base += wsum[w];
    int pos = base + x - s;   // exclusive prefix
#pragma unroll
    for (int e = 0; e < 4; e++)
        if (v[e]) kidx[b * 1024 + pos++] = t * 4 + e;
    if (t == 255) {
        int total = base + x;
        cnt[b] = total;
        padded[b] = (total + 127) & ~127;
    }
}

// ---------------------------------------------------------------------------
// Both weight transposes in one dispatch: fp32 [512,512] -> bf16 [512,512]^T
// grid (16,16,2)
// ---------------------------------------------------------------------------
__global__ __launch_bounds__(256) void transpose_w_kernel(
    const float* __restrict__ W0, const float* __restrict__ W1,
    unsigned short* __restrict__ D0, unsigned short* __restrict__ D1)
{
    __shared__ float tile[32][33];
    const float* src = blockIdx.z ? W1 : W0;
    unsigned short* dst = blockIdx.z ? D1 : D0;
    const int s0 = blockIdx.x * 32, d0 = blockIdx.y * 32;
    const int t = threadIdx.x, tr = t >> 5, tc = t & 31;
#pragma unroll
    for (int i = 0; i < 4; i++)
        tile[tr + i * 8][tc] = src[(size_t)(s0 + tr + i * 8) * 512 + d0 + tc];
    __syncthreads();
#pragma unroll
    for (int i = 0; i < 4; i++)
        dst[(size_t)(d0 + tr + i * 8) * 512 + s0 + tc] = f2bf(tile[tc][tr + i * 8]);
}

// ---------------------------------------------------------------------------
// Gather active memory rows (fp32 -> bf16): MemG[b][j][d] = memory[b][kidx[j]][d]
// for j < cnt[b], 0 for cnt<=j<padded; also transposed MemGT[b][d][j].
// grid (32, 16, 32) = (j/32, d/32, b); early-exit j0 >= padded[b].
// ---------------------------------------------------------------------------
__global__ __launch_bounds__(256) void gather_mem_kernel(
    const float* __restrict__ memory, const int* __restrict__ kidx,
    const int* __restrict__ cnt, const int* __restrict__ padded,
    unsigned short* __restrict__ MemG, unsigned short* __restrict__ MemGT)
{
    const int b = blockIdx.z;
    const int j0 = blockIdx.x * 32, d0 = blockIdx.y * 32;
    if (j0 >= padded[b]) return;
    const int nb = cnt[b];
    __shared__ float tile[32][33];
    const float* src = memory + (size_t)b * 1024 * 512;
    const int t = threadIdx.x, tr = t >> 5, tc = t & 31;
#pragma unroll
    for (int i = 0; i < 4; i++) {
        int j = j0 + tr + i * 8;
        float v = 0.f;
        if (j < nb) v = src[(size_t)kidx[b * 1024 + j] * 512 + d0 + tc];
        tile[tr + i * 8][tc] = v;
        MemG[(size_t)b * 1024 * 512 + (size_t)j * 512 + d0 + tc] = f2bf(v);
    }
    __syncthreads();
#pragma unroll
    for (int i = 0; i < 4; i++) {
        int d = d0 + tr + i * 8;
        MemGT[(size_t)b * 512 * 1024 + (size_t)d * 1024 + j0 + tc] = f2bf(tile[tc][tr + i * 8]);
    }
}

// ---------------------------------------------------------------------------
// Fused: inputs fp32 -> bf16 (proj GEMM A) AND out[..., 512:1024] = inputs
// ---------------------------------------------------------------------------
__global__ __launch_bounds__(256) void fuse_inputs_kernel(
    const float4* __restrict__ in, uint2* __restrict__ in_bf16, float4* __restrict__ out)
{
    int i = blockIdx.x * 256 + threadIdx.x;   // 4194304 float4s total
    int bq = i >> 7;
    int d  = i & 127;
    float4 v = in[i];
    out[(size_t)bq * 256 + 128 + d] = v;
    union { unsigned short u[4]; uint2 p; } pk;
    pk.u[0] = f2bf(v.x); pk.u[1] = f2bf(v.y);
    pk.u[2] = f2bf(v.z); pk.u[3] = f2bf(v.w);
    in_bf16[i] = pk.p;
}

// ---------------------------------------------------------------------------
// 128x128-tile bf16 GEMM, C = A @ Bt^T  (A: [M,K] lda, Bt: [N,K] ldb, row-major)
// CMODE 0: relu -> bf16
// CMODE 1: p = (col<cnt[z]) ? exp(acc*scale) : 0 -> bf16; rowsum += p (atomics)
// CMODE 2: acc / rowsum[row] -> fp32
// LIMA/LIMB: early-exit blocks whose A-rows / B-rows >= padded[z]
// KDYN: K-loop bound = padded[z]
// ---------------------------------------------------------------------------
template<int CMODE, int LIMA, int LIMB, int KDYN>
__global__ __launch_bounds__(256, 2) void gemm_bt(
    const unsigned short* __restrict__ A, const unsigned short* __restrict__ Bt,
    void* __restrict__ Cptr, int K, int lda, int ldb, float scale,
    const int* __restrict__ cnt, const int* __restrict__ padded,
    float* __restrict__ rowsum,
    long long aStride, long long bStride, long long cStride, int ldc)
{
    const int z = blockIdx.z;
    const int rowA = blockIdx.y * 128;
    const int rowB = blockIdx.x * 128;
    if (LIMA && rowA >= padded[z]) return;
    if (LIMB && rowB >= padded[z]) return;
    const int Kz = KDYN ? padded[z] : K;

    __shared__ __align__(16) unsigned short As[128 * 32];
    __shared__ __align__(16) unsigned short Bs[128 * 32];

    const int t = threadIdx.x;
    const int lane = t & 63;
    const int wave = t >> 6;

    const unsigned short* Ab = A + (size_t)z * aStride;
    const unsigned short* Bb = Bt + (size_t)z * bStride;

    f32x4 acc[4][4];
#pragma unroll
    for (int i = 0; i < 4; i++)
#pragma unroll
        for (int j = 0; j < 4; j++) acc[i][j] = f32x4{0.f, 0.f, 0.f, 0.f};

    const int wm = (wave >> 1) * 64;
    const int wn = (wave & 1) * 64;
    const int lrow = lane & 15;
    const int lk = (lane >> 4) * 8;

    const int sr = lane >> 2;
    const int skk = (lane & 3) * 8;
    const int c0 = wave, c1 = wave + 4;

    for (int kt = 0; kt < Kz; kt += 32) {
        const unsigned short* gb0 = Bb + (size_t)(rowB + c0 * 16 + sr) * ldb + kt + skk;
        const unsigned short* gb1 = Bb + (size_t)(rowB + c1 * 16 + sr) * ldb + kt + skk;
        __builtin_amdgcn_global_load_lds((const __attribute__((address_space(1))) void*)gb0,
                                         (__attribute__((address_space(3))) void*)&Bs[c0 * 512], 16, 0, 0);
        __builtin_amdgcn_global_load_lds((const __attribute__((address_space(1))) void*)gb1,
                                         (__attribute__((address_space(3))) void*)&Bs[c1 * 512], 16, 0, 0);
        const unsigned short* ga0 = Ab + (size_t)(rowA + c0 * 16 + sr) * lda + kt + skk;
        const unsigned short* ga1 = Ab + (size_t)(rowA + c1 * 16 + sr) * lda + kt + skk;
        __builtin_amdgcn_global_load_lds((const __attribute__((address_space(1))) void*)ga0,
                                         (__attribute__((address_space(3))) void*)&As[c0 * 512], 16, 0, 0);
        __builtin_amdgcn_global_load_lds((const __attribute__((address_space(1))) void*)ga1,
                                         (__attribute__((address_space(3))) void*)&As[c1 * 512], 16, 0, 0);
        __syncthreads();

        bf16x8 a[4], b[4];
#pragma unroll
        for (int i = 0; i < 4; i++) a[i] = *(const bf16x8*)&As[(wm + i * 16 + lrow) * 32 + lk];
#pragma unroll
        for (int j = 0; j < 4; j++) b[j] = *(const bf16x8*)&Bs[(wn + j * 16 + lrow) * 32 + lk];
#pragma unroll
        for (int i = 0; i < 4; i++)
#pragma unroll
            for (int j = 0; j < 4; j++)
                acc[i][j] = __builtin_amdgcn_mfma_f32_16x16x32_bf16(a[i], b[j], acc[i][j], 0, 0, 0);
        __syncthreads();
    }

    // epilogue: C/D layout col=lane&15, row=(lane>>4)*4+reg
    const int orow = (lane >> 4) * 4;
    const int ocol = lane & 15;

    if constexpr (CMODE == 0) {
        unsigned short* C = (unsigned short*)Cptr + (size_t)z * cStride;
#pragma unroll
        for (int i = 0; i < 4; i++)
#pragma unroll
            for (int j = 0; j < 4; j++) {
                int col = rowB + wn + j * 16 + ocol;
#pragma unroll
                for (int r = 0; r < 4; r++) {
                    int rw = rowA + wm + i * 16 + orow + r;
                    C[(size_t)rw * ldc + col] = f2bf(fmaxf(acc[i][j][r], 0.f));
                }
            }
    } else if constexpr (CMODE == 1) {
        unsigned short* C = (unsigned short*)Cptr + (size_t)z * cStride;
        const int nb = cnt[z];
        float* rs = rowsum + (size_t)z * 1024;
#pragma unroll
        for (int i = 0; i < 4; i++) {
            float part[4] = {0.f, 0.f, 0.f, 0.f};
#pragma unroll
            for (int j = 0; j < 4; j++) {
                int col = rowB + wn + j * 16 + ocol;
#pragma unroll
                for (int r = 0; r < 4; r++) {
                    float p = (col < nb) ? __expf(acc[i][j][r] * scale) : 0.f;
                    part[r] += p;
                    int rw = rowA + wm + i * 16 + orow + r;
                    C[(size_t)rw * ldc + col] = f2bf(p);
                }
            }
#pragma unroll
            for (int r = 0; r < 4; r++) {
                float s = part[r];
                s += __shfl_xor(s, 1, 64);
                s += __shfl_xor(s, 2, 64);
                s += __shfl_xor(s, 4, 64);
                s += __shfl_xor(s, 8, 64);
                if (ocol == 0) atomicAdd(&rs[rowA + wm + i * 16 + orow + r], s);
            }
        }
    } else {  // CMODE == 2
        float* C = (float*)Cptr + (size_t)z * cStride;
        const float* rs = rowsum + (size_t)z * 1024;
#pragma unroll
        for (int i = 0; i < 4; i++) {
            float inv[4];
#pragma unroll
            for (int r = 0; r < 4; r++)
                inv[r] = 1.0f / rs[rowA + wm + i * 16 + orow + r];
#pragma unroll
            for (int j = 0; j < 4; j++) {
                int col = rowB + wn + j * 16 + ocol;
#pragma unroll
                for (int r = 0; r < 4; r++) {
                    int rw = rowA + wm + i * 16 + orow + r;
                    C[(size_t)rw * ldc + col] = acc[i][j][r] * inv[r];
                }
            }
        }
    }
}

extern "C" void kernel_launch(void* const* d_in, const int* in_sizes, int n_in,
                              void* d_out, int out_size, void* d_ws, size_t ws_size,
                              hipStream_t stream)
{
    const float* inputs = (const float*)d_in[0];   // [32,1024,512]
    const float* memory = (const float*)d_in[1];   // [32,1024,512]
    const int*   mmask  = (const int*)d_in[2];     // [32,1024]
    const float* W_in   = (const float*)d_in[3];   // [512,512]
    const float* W_mem  = (const float*)d_in[4];   // [512,512]
    float* out = (float*)d_out;                    // [32,1024,1024]

    char* ws = (char*)d_ws;
    const unsigned long long MB = 1048576ull;
    unsigned short* Wt_in  = (unsigned short*)(ws);                   // 512 KiB
    unsigned short* Wt_mem = (unsigned short*)(ws + 524288);          // 512 KiB
    unsigned short* InB16  = (unsigned short*)(ws + 1 * MB);          // 32 MiB
    unsigned short* MemG   = (unsigned short*)(ws + 33 * MB);         // 32 MiB
    unsigned short* P      = (unsigned short*)(ws + 1 * MB);          // 64 MiB (alias over InB16+MemG)
    unsigned short* MemGT  = (unsigned short*)(ws + 65 * MB);         // 32 MiB
    unsigned short* Xq     = (unsigned short*)(ws + 97 * MB);         // 32 MiB
    unsigned short* Xm     = (unsigned short*)(ws + 129 * MB);        // 32 MiB
    float*          rowsum = (float*)(ws + 161 * MB);                 // 128 KiB
    int*            kidx   = (int*)(ws + 161 * MB + 131072);          // 128 KiB
    int*            cntp   = (int*)(ws + 161 * MB + 262144);          // 128 B
    int*            padp   = (int*)(ws + 161 * MB + 262144 + 128);    // 128 B

    const float scale = 0.04419417382415922f;  // 1/sqrt(512)

    // 1. mask compaction + weight transposes
    mask_scan_kernel<<<32, 256, 0, stream>>>(mmask, kidx, cntp, padp);
    transpose_w_kernel<<<dim3(16, 16, 2), 256, 0, stream>>>(W_in, W_mem, Wt_in, Wt_mem);

    // 2. gather active memory rows -> MemG (bf16) + MemGT (bf16, transposed)
    gather_mem_kernel<<<dim3(32, 16, 32), 256, 0, stream>>>(
        memory, kidx, cntp, padp, MemG, MemGT);

    // 3. inputs -> bf16 + concat right half of out
    fuse_inputs_kernel<<<16384, 256, 0, stream>>>(
        (const float4*)inputs, (uint2*)InB16, (float4*)out);

    // zero rowsum (poisoned every launch)
    hipMemsetAsync(rowsum, 0, 32 * 1024 * sizeof(float), stream);

    // 4. projections: Xq = relu(inputs @ W_in)  [full M]
    gemm_bt<0, 0, 0, 0><<<dim3(4, 256, 1), 256, 0, stream>>>(
        InB16, Wt_in, Xq, 512, 512, 512, 0.f, nullptr, nullptr, nullptr,
        0, 0, 0, 512);
    //    Xm = relu(MemG @ W_mem)  [only active rows, early-exit on padded]
    gemm_bt<0, 1, 0, 0><<<dim3(4, 8, 32), 256, 0, stream>>>(
        MemG, Wt_mem, Xm, 512, 512, 512, 0.f, nullptr, padp, nullptr,
        1024ll * 512, 0, 1024ll * 512, 512);

    // 5. P = exp(Xq @ Xm^T * scale) for col<cnt, else 0; rowsum atomics
    gemm_bt<1, 0, 1, 0><<<dim3(8, 8, 32), 256, 0, stream>>>(
        Xq, Xm, P, 512, 512, 512, scale, cntp, padp, rowsum,
        1024ll * 512, 1024ll * 512, 1024ll * 1024, 1024);

    // 6. context = (P @ MemGT^T) / rowsum -> fp32 out[..., 0:512], K = padded[b]
    gemm_bt<2, 0, 0, 1><<<dim3(4, 8, 32), 256, 0, stream>>>(
        P, MemGT, out, 1024, 1024, 1024, 1.f, nullptr, padp, rowsum,
        1024ll * 1024, 512ll * 1024, 1024ll * 1024, 1024);
}